// Round 1
// 175.593 us; speedup vs baseline: 1.0209x; 1.0209x over previous
//
#include <hip/hip_runtime.h>

// B=16, D=256, L=256, T=1000, K=3, DW=4, DC=2, CH=8

typedef short v8s __attribute__((ext_vector_type(8)));
typedef _Float16 v8h __attribute__((ext_vector_type(8)));
typedef float f4 __attribute__((ext_vector_type(4)));

__device__ __forceinline__ float bf2f(unsigned short h) {
  return __uint_as_float(((unsigned int)h) << 16);
}
__device__ __forceinline__ unsigned short f2bf(float f) {
  unsigned int u = __float_as_uint(f);
  u = (u + 0x7FFFu + ((u >> 16) & 1u)) >> 16;
  return (unsigned short)u;
}
__device__ __forceinline__ float swishf(float x) {
  return x * __builtin_amdgcn_rcpf(1.f + __expf(-x));
}

// =======================================================================
// K_PREP: level-0 work, branch on blockIdx.x
// =======================================================================
__global__ __launch_bounds__(256) void k_prep(
    const float* __restrict__ dur, const float* __restrict__ ph,
    const float* __restrict__ liWw,
    const float* __restrict__ cvWw, const float* __restrict__ pjWw,
    const float* __restrict__ pjbw,
    const float* __restrict__ cvWc, const float* __restrict__ pjWc,
    const float* __restrict__ pjbc,
    float* __restrict__ sk, int* __restrict__ frame_len,
    unsigned short* __restrict__ Mb, float* __restrict__ bK,
    unsigned short* __restrict__ LWT, unsigned short* __restrict__ phT) {
  __shared__ float sm[32 * 33];
  int blk = blockIdx.x, tid = threadIdx.x;
  if (blk < 16) {
    int b = blk, l = tid;
    float d = dur[b * 256 + l];
    sm[l] = d;
    __syncthreads();
    for (int off = 1; off < 256; off <<= 1) {
      float v = (l >= off) ? sm[l - off] : 0.f;
      __syncthreads();
      sm[l] += v;
      __syncthreads();
    }
    sk[b * 256 + l] = sm[l] - d;
    if (l == 255) {
      int fl = (int)rintf(sm[255]);
      frame_len[b] = min(max(fl, 0), 1000);
    }
  } else if (blk < 64) {
    int x = blk - 16;
    int br = x / 24, ck = x % 24;
    int ch = ck / 3, k = ck % 3;
    const float* convW = br ? cvWc : cvWw;
    const float* projW = br ? pjWc : pjWw;
    const float* projb = br ? pjbc : pjbw;
    int d = tid;
    // 4 independent chains so the 256-deep K loop pipelines
    float a0 = 0.f, a1 = 0.f, a2 = 0.f, a3 = 0.f;
    for (int o = 0; o < 256; o += 4) {
      a0 += convW[ch * 768 + (o + 0) * 3 + k] * projW[(o + 0) * 256 + d];
      a1 += convW[ch * 768 + (o + 1) * 3 + k] * projW[(o + 1) * 256 + d];
      a2 += convW[ch * 768 + (o + 2) * 3 + k] * projW[(o + 2) * 256 + d];
      a3 += convW[ch * 768 + (o + 3) * 3 + k] * projW[(o + 3) * 256 + d];
    }
    Mb[(br * 24 + ck) * 256 + d] = f2bf((a0 + a1) + (a2 + a3));
    if (tid < 64) {
      // wave-parallel bias reduction (was a 256-iter single-lane loop)
      float pb = 0.f;
      for (int o = tid; o < 256; o += 64)
        pb += convW[ch * 768 + o * 3 + k] * projb[o];
#pragma unroll
      for (int off = 1; off < 64; off <<= 1) pb += __shfl_xor(pb, off);
      if (tid == 0) bK[br * 24 + ck] = pb;
    }
  } else if (blk < 320) {
    int idx = blk - 64;
    int kt = idx & 31, ot = idx >> 5;
    int tx = tid & 31, ty = tid >> 5;
#pragma unroll
    for (int r = 0; r < 4; r++) {
      int row = ty + r * 8;
      sm[row * 33 + tx] = liWw[(size_t)(kt * 32 + row) * 256 + ot * 32 + tx];
    }
    __syncthreads();
#pragma unroll
    for (int r = 0; r < 4; r++) {
      int row = ty + r * 8;
      LWT[(size_t)(ot * 32 + row) * 1024 + kt * 32 + tx] =
          f2bf(sm[tx * 33 + row]);
    }
  } else {
    int idx = blk - 320;
    int ht = idx & 7, lt = (idx >> 3) & 7, b = idx >> 6;
    int tx = tid & 31, ty = tid >> 5;
#pragma unroll
    for (int r = 0; r < 4; r++) {
      int row = ty + r * 8;
      sm[row * 33 + tx] =
          ph[(size_t)b * 65536 + (size_t)(ht * 32 + row) * 256 + lt * 32 + tx];
    }
    __syncthreads();
#pragma unroll
    for (int r = 0; r < 4; r++) {
      int row = ty + r * 8;
      phT[(size_t)b * 65536 + (size_t)(lt * 32 + row) * 256 + ht * 32 + tx] =
          f2bf(sm[tx * 33 + row]);
    }
  }
}

// =======================================================================
// K_CONVG: blk [0,16)   = MFMA conv -> per-l MLP bases (Lbw/Laux/maxA)
//          blk [16,272) = gemmG, barrier-less, frags direct from L2
// =======================================================================
__global__ __launch_bounds__(256) void k_convG(
    const unsigned short* __restrict__ phT, const unsigned short* __restrict__ Mb,
    const float* __restrict__ bK, const float* __restrict__ cvbw,
    const float* __restrict__ cvbc, const float* __restrict__ dur,
    const float* __restrict__ sk, const float* __restrict__ mlpWw,
    const float* __restrict__ mlpbw, const float* __restrict__ mlpWc,
    const float* __restrict__ mlpbc, const unsigned short* __restrict__ LWT,
    float* __restrict__ Lbw, float* __restrict__ Laux,
    float* __restrict__ maxAb, _Float16* __restrict__ G) {
  __shared__ __align__(16) float C[256 * 49];
  __shared__ float redm[4][4];
  int blk = blockIdx.x;
  int tid = threadIdx.x, wave = tid >> 6, lane = tid & 63;
  int quad = lane >> 4, col = lane & 15;
  if (blk < 16) {
    int b = blk;
    int l0 = wave * 64;
    const unsigned short* Ab = phT + (size_t)b * 65536;
    f4 acc[4][3] = {};
#pragma unroll
    for (int k0 = 0; k0 < 256; k0 += 32) {
      v8s af[4], bf[3];
#pragma unroll
      for (int lt = 0; lt < 4; lt++)
        af[lt] = *(const v8s*)(Ab + (size_t)(l0 + lt * 16 + col) * 256 + k0 + quad * 8);
#pragma unroll
      for (int ct = 0; ct < 3; ct++)
        bf[ct] = *(const v8s*)(Mb + (size_t)(ct * 16 + col) * 256 + k0 + quad * 8);
#pragma unroll
      for (int lt = 0; lt < 4; lt++)
#pragma unroll
        for (int ct = 0; ct < 3; ct++)
          acc[lt][ct] = __builtin_amdgcn_mfma_f32_16x16x32_bf16(af[lt], bf[ct],
                                                                acc[lt][ct], 0, 0, 0);
    }
#pragma unroll
    for (int lt = 0; lt < 4; lt++)
#pragma unroll
      for (int ct = 0; ct < 3; ct++)
#pragma unroll
        for (int r = 0; r < 4; r++)
          C[(l0 + lt * 16 + quad * 4 + r) * 49 + ct * 16 + col] = acc[lt][ct][r];
    __syncthreads();
    int l = tid;
    float dv = dur[b * 256 + l];
    bool vld = (dv != 0.f);
    float hv[2][8];
#pragma unroll
    for (int br = 0; br < 2; br++) {
      const float* convb = br ? cvbc : cvbw;
#pragma unroll
      for (int ch = 0; ch < 8; ch++) {
        int ck = br * 24 + ch * 3;
        float v = convb[ch] + bK[ck + 1] + C[l * 49 + ck + 1];
        if (l > 0) v += bK[ck + 0] + C[(l - 1) * 49 + ck + 0];
        if (l < 255) v += bK[ck + 2] + C[(l + 1) * 49 + ck + 2];
        hv[br][ch] = vld ? swishf(v) : 0.f;
      }
    }
    float skl = sk[b * 256 + l];
    float A[4];
#pragma unroll
    for (int q = 0; q < 4; q++) {
      float a = mlpbw[q] + dv * mlpWw[4 + q] - skl * mlpWw[q];
#pragma unroll
      for (int ch = 0; ch < 8; ch++) a += hv[0][ch] * mlpWw[(2 + ch) * 4 + q];
      A[q] = vld ? a : -1e30f;
    }
    float bb0 = mlpbc[0] + dv * mlpWc[2] - skl * mlpWc[0];
    float bb1 = mlpbc[1] + dv * mlpWc[3] - skl * mlpWc[1];
#pragma unroll
    for (int ch = 0; ch < 8; ch++) {
      bb0 += hv[1][ch] * mlpWc[(2 + ch) * 2 + 0];
      bb1 += hv[1][ch] * mlpWc[(2 + ch) * 2 + 1];
    }
    float4 Av = {A[0], A[1], A[2], A[3]};
    ((float4*)Lbw)[b * 256 + l] = Av;
    float4 Xv = {bb0, bb1, vld ? 1.f : 0.f, 0.f};
    ((float4*)Laux)[b * 256 + l] = Xv;
    // per-b max over l for each q
    float m0 = A[0], m1 = A[1], m2 = A[2], m3 = A[3];
#pragma unroll
    for (int off = 1; off < 64; off <<= 1) {
      m0 = fmaxf(m0, __shfl_xor(m0, off));
      m1 = fmaxf(m1, __shfl_xor(m1, off));
      m2 = fmaxf(m2, __shfl_xor(m2, off));
      m3 = fmaxf(m3, __shfl_xor(m3, off));
    }
    if (lane == 0) {
      redm[wave][0] = m0;
      redm[wave][1] = m1;
      redm[wave][2] = m2;
      redm[wave][3] = m3;
    }
    __syncthreads();
    if (tid < 4)
      maxAb[b * 4 + tid] = fmaxf(fmaxf(redm[0][tid], redm[1][tid]),
                                 fmaxf(redm[2][tid], redm[3][tid]));
  } else {
    int idx = blk - 16;
    int b = idx >> 4;
    int sub = idx & 15;
    int q = sub >> 2, quadr = sub & 3;
    int mo = (quadr >> 1) * 128, nl = (quadr & 1) * 128;
    int wm = (wave & 1) * 64, wn = (wave >> 1) * 64;
    const unsigned short* Ag = LWT + (size_t)q * 256;
    const unsigned short* Bg = phT + (size_t)b * 65536;
    f4 acc[4][4] = {};
#pragma unroll
    for (int k0 = 0; k0 < 256; k0 += 32) {
      v8s af[4], bf[4];
#pragma unroll
      for (int mt = 0; mt < 4; mt++)
        af[mt] = *(const v8s*)(Ag + (size_t)(mo + wm + mt * 16 + col) * 1024 +
                               k0 + quad * 8);
#pragma unroll
      for (int nt = 0; nt < 4; nt++)
        bf[nt] = *(const v8s*)(Bg + (size_t)(nl + wn + nt * 16 + col) * 256 +
                               k0 + quad * 8);
#pragma unroll
      for (int mt = 0; mt < 4; mt++)
#pragma unroll
        for (int nt = 0; nt < 4; nt++)
          acc[mt][nt] = __builtin_amdgcn_mfma_f32_16x16x32_bf16(af[mt], bf[nt],
                                                                acc[mt][nt], 0, 0, 0);
    }
    _Float16* Gb = G + (size_t)b * 262144 + q * 256;
#pragma unroll
    for (int mt = 0; mt < 4; mt++)
#pragma unroll
      for (int r = 0; r < 4; r++) {
        int orow = mo + wm + mt * 16 + quad * 4 + r;
#pragma unroll
        for (int nt = 0; nt < 4; nt++) {
          int lcol = nl + wn + nt * 16 + col;
          Gb[(size_t)orow * 1024 + lcol] = (_Float16)acc[mt][nt][r];
        }
      }
  }
}

// =======================================================================
// K_FUSE: softmax (w tile in LDS, q-split into 2 passes of 512 cols) fused
// with the output GEMM. B-frags direct from L2; XCD-aware b mapping keeps
// each XCD's working set to 2 G-slices (1 MB). w never touches HBM.
// grid 512 (= 16 b x 32 t-tiles of 32 rows), 256 threads.
// =======================================================================
__global__ __launch_bounds__(256) void k_fuse(
    const float* __restrict__ Lbw, const float* __restrict__ Laux,
    const float* __restrict__ maxAb, const int* __restrict__ frame_len,
    const float* __restrict__ mlpWw, const float* __restrict__ mlpWc,
    const _Float16* __restrict__ G, const float* __restrict__ lwb,
    const float* __restrict__ lcb, const float* __restrict__ LC,
    float* __restrict__ out) {
  __shared__ __align__(16) _Float16 Asm[32 * 512];  // XOR-swizzled w tile
  __shared__ __align__(16) float4 Lb4[264];         // padded: l + (l>>5)
  __shared__ __align__(16) float4 Lx4[264];
  __shared__ float bias_s[256];
  __shared__ float lcs[8][256];
  __shared__ float wcs[32][8];

  int idx = blockIdx.x;
  // XCD-aware: blocks with the same (idx % 8) residue share b -> G slice
  // stays resident in that XCD's L2.
  int b = (idx & 7) * 2 + ((idx >> 3) & 1);
  int t0 = (idx >> 4) * 32;
  int tid = threadIdx.x, wave = tid >> 6, lane = tid & 63;
  int quad = lane >> 4, col = lane & 15;

  {
    float4 av = ((const float4*)Lbw)[b * 256 + tid];
    float4 xv = ((const float4*)Laux)[b * 256 + tid];
    int li = tid + (tid >> 5);
    Lb4[li] = av;
    Lx4[li] = xv;
    bias_s[tid] = lwb[tid] + lcb[tid];
#pragma unroll
    for (int i = 0; i < 8; i++) lcs[i][tid] = LC[i * 256 + tid];
  }
  int fl = frame_len[b];
  float4 mx4 = ((const float4*)maxAb)[b];
  float mw0 = mlpWw[0], mw1 = mlpWw[1], mw2 = mlpWw[2], mw3 = mlpWw[3];
  float mc0 = mlpWc[0], mc1 = mlpWc[1];

  int r_loc = lane >> 3, l_grp = lane & 7;
  int row = wave * 8 + r_loc;  // softmax row owned by this thread
  int t = t0 + row;
  bool live = (t < fl);
  float tp1 = (float)(t + 1);
  int rsw = row & 7;
  int asw = col & 7;
  int wn = wave * 64;  // waves split 1x4 over N: no B-frag duplication
  f4 acc[2][4] = {};

  __syncthreads();

#pragma unroll
  for (int p = 0; p < 2; ++p) {
    if (p) __syncthreads();  // pass-0 GEMM done reading Asm
    float mq0 = p ? mw2 : mw0;
    float mq1 = p ? mw3 : mw1;
    float mxa = p ? mx4.z : mx4.x;
    float mxb = p ? mx4.w : mx4.y;
    float m0 = live ? fmaxf(mxa + tp1 * mq0, 0.f) : 1e30f;
    float m1 = live ? fmaxf(mxb + tp1 * mq1, 0.f) : 1e30f;
    float s0 = 0.f, s1 = 0.f, p00 = 0.f, p01 = 0.f, p10 = 0.f, p11 = 0.f;
    v8h e0[4], e1[4];
#pragma unroll
    for (int j = 0; j < 32; ++j) {
      int l = l_grp * 32 + j;
      int li = l + (l >> 5);
      float4 A4 = Lb4[li];
      float4 ax = Lx4[li];
      float cp0 = swishf(ax.x + tp1 * mc0);
      float cp1 = swishf(ax.y + tp1 * mc1);
      float Aq0 = p ? A4.z : A4.x;
      float Aq1 = p ? A4.w : A4.y;
      float ee0 = __expf(swishf(Aq0 + tp1 * mq0) - m0) * ax.z;
      float ee1 = __expf(swishf(Aq1 + tp1 * mq1) - m1) * ax.z;
      e0[j >> 3][j & 7] = (_Float16)ee0;
      e1[j >> 3][j & 7] = (_Float16)ee1;
      s0 += ee0;
      s1 += ee1;
      p00 += ee0 * cp0;
      p01 += ee0 * cp1;
      p10 += ee1 * cp0;
      p11 += ee1 * cp1;
    }
#pragma unroll
    for (int off = 1; off < 8; off <<= 1) {
      s0 += __shfl_xor(s0, off);
      s1 += __shfl_xor(s1, off);
      p00 += __shfl_xor(p00, off);
      p01 += __shfl_xor(p01, off);
      p10 += __shfl_xor(p10, off);
      p11 += __shfl_xor(p11, off);
    }
    float iv0 = live ? __builtin_amdgcn_rcpf(s0) : 0.f;
    float iv1 = live ? __builtin_amdgcn_rcpf(s1) : 0.f;
    if (l_grp == 0) {
      wcs[row][p * 4 + 0] = p00 * iv0;
      wcs[row][p * 4 + 1] = p01 * iv0;
      wcs[row][p * 4 + 2] = p10 * iv1;
      wcs[row][p * 4 + 3] = p11 * iv1;
    }
    _Float16 h0 = (_Float16)iv0, h1 = (_Float16)iv1;
#pragma unroll
    for (int c = 0; c < 4; ++c) {
      int sl0 = (l_grp * 4 + c) ^ rsw;
      int sl1 = 32 + ((l_grp * 4 + c) ^ rsw);
      *(v8h*)&Asm[(row * 64 + sl0) * 8] = e0[c] * h0;
      *(v8h*)&Asm[(row * 64 + sl1) * 8] = e1[c] * h1;
    }
    __syncthreads();
    const _Float16* Gp = G + (size_t)b * 262144 + p * 512;
#pragma unroll 2
    for (int k0 = 0; k0 < 512; k0 += 32) {
      int slk = (k0 >> 3) + quad;
      v8h af0 = *(const v8h*)&Asm[(col * 64 + (slk ^ asw)) * 8];
      v8h af1 = *(const v8h*)&Asm[((16 + col) * 64 + (slk ^ asw)) * 8];
      v8h bf[4];
#pragma unroll
      for (int nt = 0; nt < 4; ++nt)
        bf[nt] =
            *(const v8h*)(Gp + (size_t)(wn + nt * 16 + col) * 1024 + k0 + quad * 8);
#pragma unroll
      for (int nt = 0; nt < 4; ++nt) {
        acc[0][nt] =
            __builtin_amdgcn_mfma_f32_16x16x32_f16(af0, bf[nt], acc[0][nt], 0, 0, 0);
        acc[1][nt] =
            __builtin_amdgcn_mfma_f32_16x16x32_f16(af1, bf[nt], acc[1][nt], 0, 0, 0);
      }
    }
  }
#pragma unroll
  for (int mt = 0; mt < 2; ++mt)
#pragma unroll
    for (int r = 0; r < 4; ++r) {
      int lrow = mt * 16 + quad * 4 + r;
      int trow = t0 + lrow;
      if (trow < 1000) {
        float4 wa = *(const float4*)&wcs[lrow][0];
        float4 wb = *(const float4*)&wcs[lrow][4];
        float wcl[8] = {wa.x, wa.y, wa.z, wa.w, wb.x, wb.y, wb.z, wb.w};
#pragma unroll
        for (int nt = 0; nt < 4; ++nt) {
          int oc = wn + nt * 16 + col;
          float v = acc[mt][nt][r] + bias_s[oc];
#pragma unroll
          for (int jj = 0; jj < 8; ++jj) v = fmaf(wcl[jj], lcs[jj][oc], v);
          out[((size_t)(b * 1000 + trow)) * 256 + oc] = v;
        }
      }
    }
}

// ---------- launch ----------
extern "C" void kernel_launch(void* const* d_in, const int* in_sizes, int n_in,
                              void* d_out, int out_size, void* d_ws, size_t ws_size,
                              hipStream_t stream) {
  const float* dur  = (const float*)d_in[0];
  const float* ph   = (const float*)d_in[1];
  const float* pjWw = (const float*)d_in[3];
  const float* pjbw = (const float*)d_in[4];
  const float* cvWw = (const float*)d_in[5];
  const float* cvbw = (const float*)d_in[6];
  const float* mlWw = (const float*)d_in[7];
  const float* mlbw = (const float*)d_in[8];
  const float* liWw = (const float*)d_in[9];
  const float* libw = (const float*)d_in[10];
  const float* pjWc = (const float*)d_in[11];
  const float* pjbc = (const float*)d_in[12];
  const float* cvWc = (const float*)d_in[13];
  const float* cvbc = (const float*)d_in[14];
  const float* mlWc = (const float*)d_in[15];
  const float* mlbc = (const float*)d_in[16];
  const float* liWc = (const float*)d_in[17];
  const float* libc = (const float*)d_in[18];
  float* out = (float*)d_out;

  float* f = (float*)d_ws;
  size_t o = 0;
  float* sk = f + o;            o += 4096;
  int* fl = (int*)(f + o);      o += 16;
  float* bK = f + o;            o += 64;
  unsigned short* Mb = (unsigned short*)(f + o); o += 6144;
  float* Lbw = f + o;           o += 16384;   // [b][l] float4 MLP bases (w)
  float* Laux = f + o;          o += 16384;   // [b][l] {bb0, bb1, msk, -}
  float* mxA = f + o;           o += 64;      // [b][4] max_l A
  _Float16* G = (_Float16*)(f + o);              o += 2097152;  // 8.4 MB
  unsigned short* phT = (unsigned short*)(f + o); o += 524288;
  unsigned short* LWT = (unsigned short*)(f + o); o += 131072;

  k_prep<<<1344, 256, 0, stream>>>(dur, ph, liWw, cvWw, pjWw, pjbw, cvWc, pjWc,
                                   pjbc, sk, fl, Mb, bK, LWT, phT);
  k_convG<<<272, 256, 0, stream>>>(phT, Mb, bK, cvbw, cvbc, dur, sk, mlWw,
                                   mlbw, mlWc, mlbc, LWT, Lbw, Laux, mxA, G);
  k_fuse<<<512, 256, 0, stream>>>(Lbw, Laux, mxA, fl, mlWw, mlWc, G, libw,
                                  libc, liWc, out);
}